// Round 7
// baseline (159.963 us; speedup 1.0000x reference)
//
#include <hip/hip_runtime.h>
#include <hip/hip_bf16.h>

typedef unsigned short u16;
typedef unsigned int u32;
typedef __bf16 bf16x8 __attribute__((ext_vector_type(8)));
typedef float f32x4 __attribute__((ext_vector_type(4)));

#define N_ROWS 8192
#define DIM 512
#define BM 128
#define BN 128
#define BK 64
#define NTILES 2080        // 64*65/2 upper-triangular tiles
#define NREP 8             // accumulator replicas
#define TEMP_INV (1.0f / 0.07f)

// round-to-nearest-even float -> bf16 bit pattern
__device__ __forceinline__ u16 f2bf(float f) {
    union { float f; u32 u; } a;
    a.f = f;
    u32 r = a.u + 0x7FFFu + ((a.u >> 16) & 1u);
    return (u16)(r >> 16);
}

// ------- kernel 1: L2-normalize rows -> bf16; zero accs; build schedule ----
// Schedule: tiles grouped by g = tj&7 (column-major inside a group), groups
// interleaved round-robin => slot ~= g (mod 8) for ~89% of slots. Round-robin
// dispatch then pins each XCD to its 8 B-columns (R4-proven locality) while
// every CU gets 8+-1 live tiles (fixes R4's 0..16 imbalance).
__global__ __launch_bounds__(256) void norm_cast_kernel(
        const float* __restrict__ x, u16* __restrict__ hb,
        float* __restrict__ accR /* 2*NREP*N_ROWS floats */,
        u32* __restrict__ order, float* __restrict__ out) {
    int gid = blockIdx.x * 256 + threadIdx.x;
    if (gid < 2 * NREP * N_ROWS) accR[gid] = 0.f;
    if (gid == 0) out[0] = 0.f;
    if (gid < NTILES) {
        // decode gid -> (ti, tj): column-major upper triangle (ti <= tj)
        int tj = (int)((sqrtf(8.0f * (float)gid + 1.0f) - 1.0f) * 0.5f);
        while ((tj + 1) * (tj + 2) / 2 <= gid) ++tj;
        while (tj * (tj + 1) / 2 > gid) --tj;
        int ti = gid - tj * (tj + 1) / 2;
        // in-group index k (column-major within group g)
        int g = tj & 7;
        int n = tj >> 3;                       // columns of group g before tj
        int k = n * (g + 1 + 4 * (n - 1)) + ti;
        // slot of list_g[k] in the round-robin merge; group sizes s_g = 8g+232
        int slot = 0;
#pragma unroll
        for (int g2 = 0; g2 < 8; ++g2) {
            int s2 = 8 * g2 + 232;
            slot += (k < s2) ? k : s2;
            if (g2 < g && s2 > k) ++slot;
        }
        order[slot] = (u32)((ti << 8) | tj);
    }
    int row  = blockIdx.x * 4 + (threadIdx.x >> 6);
    int lane = threadIdx.x & 63;
    const float4* xr = (const float4*)(x + (size_t)row * DIM);
    float4 v0 = xr[lane * 2 + 0];
    float4 v1 = xr[lane * 2 + 1];
    float ss = v0.x * v0.x + v0.y * v0.y + v0.z * v0.z + v0.w * v0.w
             + v1.x * v1.x + v1.y * v1.y + v1.z * v1.z + v1.w * v1.w;
#pragma unroll
    for (int off = 32; off; off >>= 1) ss += __shfl_xor(ss, off);
    float s = 1.0f / fmaxf(sqrtf(ss), 1e-12f);
    uint4 o;
    o.x = (u32)f2bf(v0.x * s) | ((u32)f2bf(v0.y * s) << 16);
    o.y = (u32)f2bf(v0.z * s) | ((u32)f2bf(v0.w * s) << 16);
    o.z = (u32)f2bf(v1.x * s) | ((u32)f2bf(v1.y * s) << 16);
    o.w = (u32)f2bf(v1.z * s) | ((u32)f2bf(v1.w * s) << 16);
    ((uint4*)(hb + (size_t)row * DIM))[lane] = o;
}

// ------- kernel 2: triangular fused tile GEMM + exp + sums -----------------
// R4's kernel body unchanged (16.5K cyc/tile proven on max-loaded CUs);
// work assignment now via LUT: balance + XCD locality simultaneously.
__global__ __launch_bounds__(256) void tile_kernel(
        const u16* __restrict__ hb, const int* __restrict__ labels,
        const u32* __restrict__ order,
        float* __restrict__ rowTotalR, float* __restrict__ rowPosR) {
    __shared__ __align__(16) u16 ldsA[BM * BK];
    __shared__ __align__(16) u16 ldsB[BN * BK];
    __shared__ int labR[BM];
    __shared__ int labC[BN];
    __shared__ float cT[2][BN], cP[2][BN];   // per wave-row column sums
    __shared__ float rT[2][BM], rP[2][BM];   // per wave-col row sums

    const u32 ord = order[blockIdx.x];
    const int ti = (int)(ord >> 8);
    const int tj = (int)(ord & 255u);
    const int rowBase = ti * BM;
    const int colBase = tj * BN;
    const bool isDiag = (ti == tj);
    const int dd = colBase - rowBase;        // diag element iff rloc - cloc == dd
    const int rep = (ti + tj) & (NREP - 1);
    const int tid = threadIdx.x;

    if (tid < 128) labR[tid] = labels[rowBase + tid];
    else           labC[tid - 128] = labels[colBase + tid - 128];

    const int w = tid >> 6;
    const int lane = tid & 63;
    const int wm = (w >> 1) * 64;   // wave row offset in tile
    const int wn = (w & 1) * 64;    // wave col offset in tile
    const int wr = w >> 1;
    const int wc = w & 1;
    const int quad = lane >> 4;
    const int l16 = lane & 15;
    const int sw = l16 & 7;         // xor-swizzle key

    f32x4 acc[4][4];
#pragma unroll
    for (int i = 0; i < 4; ++i)
#pragma unroll
        for (int j = 0; j < 4; ++j)
            acc[i][j] = (f32x4){0.f, 0.f, 0.f, 0.f};

    for (int k0 = 0; k0 < DIM; k0 += BK) {
        // stage tiles; 16 B chunks xor-swizzled within each 128 B row
#pragma unroll
        for (int s = 0; s < 4; ++s) {
            int seg = tid + s * 256;          // 0..1023
            int r = seg >> 3;                 // 0..127
            int c8 = seg & 7;                 // chunk slot in LDS
            int gc = (k0 >> 3) + (c8 ^ (r & 7));
            const u16* ga = hb + (size_t)(rowBase + r) * DIM + gc * 8;
            const u16* gb = hb + (size_t)(colBase + r) * DIM + gc * 8;
            __builtin_amdgcn_global_load_lds(
                (const __attribute__((address_space(1))) void*)ga,
                (__attribute__((address_space(3))) void*)&ldsA[seg * 8], 16, 0, 0);
            __builtin_amdgcn_global_load_lds(
                (const __attribute__((address_space(1))) void*)gb,
                (__attribute__((address_space(3))) void*)&ldsB[seg * 8], 16, 0, 0);
        }
        __syncthreads();
#pragma unroll
        for (int kk8 = 0; kk8 < 8; kk8 += 4) {   // two K=32 steps
            bf16x8 af[4], bfr[4];
#pragma unroll
            for (int im = 0; im < 4; ++im)
                af[im] = *(const bf16x8*)
                    &ldsA[(wm + im * 16 + l16) * BK + (((kk8 + quad) ^ sw) * 8)];
#pragma unroll
            for (int in = 0; in < 4; ++in)
                bfr[in] = *(const bf16x8*)
                    &ldsB[(wn + in * 16 + l16) * BK + (((kk8 + quad) ^ sw) * 8)];
#pragma unroll
            for (int im = 0; im < 4; ++im)
#pragma unroll
                for (int in = 0; in < 4; ++in)
                    acc[im][in] = __builtin_amdgcn_mfma_f32_16x16x32_bf16(
                        af[im], bfr[in], acc[im][in], 0, 0, 0);
        }
        __syncthreads();
    }

    // ---------------- epilogue ----------------
    // C/D layout: col = l16, row = quad*4 + reg (within each 16x16 frag)
    int lc[4];
#pragma unroll
    for (int in = 0; in < 4; ++in) lc[in] = labC[wn + in * 16 + l16];

    float colT[4] = {0.f, 0.f, 0.f, 0.f}, colP[4] = {0.f, 0.f, 0.f, 0.f};
#pragma unroll
    for (int im = 0; im < 4; ++im) {
        float rowT[4] = {0.f, 0.f, 0.f, 0.f}, rowP[4] = {0.f, 0.f, 0.f, 0.f};
#pragma unroll
        for (int reg = 0; reg < 4; ++reg) {
            int rloc = wm + im * 16 + quad * 4 + reg;
            int li = labR[rloc];
#pragma unroll
            for (int in = 0; in < 4; ++in) {
                int cloc = wn + in * 16 + l16;
                float e = __expf(acc[im][in][reg] * TEMP_INV);
                bool pos = (lc[in] == li) && (rloc - cloc != dd);
                colT[in] += e; rowT[reg] += e;
                if (pos) { colP[in] += e; rowP[reg] += e; }
            }
        }
        if (!isDiag) {
#pragma unroll
            for (int reg = 0; reg < 4; ++reg) {
                float t = rowT[reg], p = rowP[reg];
                t += __shfl_xor(t, 1); t += __shfl_xor(t, 2);
                t += __shfl_xor(t, 4); t += __shfl_xor(t, 8);
                p += __shfl_xor(p, 1); p += __shfl_xor(p, 2);
                p += __shfl_xor(p, 4); p += __shfl_xor(p, 8);
                if (l16 == 0) {
                    int rloc = wm + im * 16 + quad * 4 + reg;
                    rT[wc][rloc] = t;   // distinct rloc per (im,quad,reg)
                    rP[wc][rloc] = p;
                }
            }
        }
    }
#pragma unroll
    for (int in = 0; in < 4; ++in) {
        float t = colT[in], p = colP[in];
        t += __shfl_xor(t, 16); t += __shfl_xor(t, 32);
        p += __shfl_xor(p, 16); p += __shfl_xor(p, 32);
        if (quad == 0) {
            int cloc = wn + in * 16 + l16;
            cT[wr][cloc] = t;
            cP[wr][cloc] = p;
        }
    }
    __syncthreads();
    float* rowTotal = rowTotalR + rep * N_ROWS;
    float* rowPos   = rowPosR   + rep * N_ROWS;
    if (tid < 128) {
        atomicAdd(&rowTotal[colBase + tid], cT[0][tid] + cT[1][tid]);
        if (!isDiag) atomicAdd(&rowTotal[rowBase + tid], rT[0][tid] + rT[1][tid]);
    } else {
        int t2 = tid - 128;
        atomicAdd(&rowPos[colBase + t2], cP[0][t2] + cP[1][t2]);
        if (!isDiag) atomicAdd(&rowPos[rowBase + t2], rP[0][t2] + rP[1][t2]);
    }
}

// ------- kernel 3: fold replicas + histogram + loss (64 blocks) ------------
__global__ __launch_bounds__(256) void reduce_loss_kernel(
        const int* __restrict__ labels, const float* __restrict__ rowTotalR,
        const float* __restrict__ rowPosR, float* __restrict__ out) {
    __shared__ int hist[128];
    __shared__ float red[256];
    int tid = threadIdx.x;
    if (tid < 128) hist[tid] = 0;
    __syncthreads();
    for (int i = tid; i < N_ROWS; i += 256)
        atomicAdd(&hist[labels[i] & 127], 1);
    __syncthreads();
    float sacc = 0.f;
    if (tid < 128) {
        int row = blockIdx.x * 128 + tid;
        float T = 0.f, P = 0.f;
#pragma unroll
        for (int r = 0; r < NREP; ++r) {
            T += rowTotalR[r * N_ROWS + row];
            P += rowPosR[r * N_ROWS + row];
        }
        float c = (float)(hist[labels[row] & 127] - 1);
        sacc = logf((P / (c + 1e-9f)) / T);
    }
    red[tid] = sacc;
    __syncthreads();
    for (int st = 128; st; st >>= 1) {
        if (tid < st) red[tid] += red[tid + st];
        __syncthreads();
    }
    if (tid == 0) atomicAdd(out, -red[0] / (float)N_ROWS);
}

extern "C" void kernel_launch(void* const* d_in, const int* in_sizes, int n_in,
                              void* d_out, int out_size, void* d_ws, size_t ws_size,
                              hipStream_t stream) {
    const float* hidden = (const float*)d_in[0];
    const int* labels   = (const int*)d_in[1];
    float* out = (float*)d_out;

    char* ws = (char*)d_ws;
    u16* hb = (u16*)ws;                                          // 8 MB
    float* rowTotalR = (float*)(ws + (size_t)N_ROWS * DIM * 2);  // NREP*8192 f
    float* rowPosR   = rowTotalR + NREP * N_ROWS;                // NREP*8192 f
    u32* order       = (u32*)(rowPosR + NREP * N_ROWS);          // 2080 u32

    norm_cast_kernel<<<N_ROWS / 4, 256, 0, stream>>>(hidden, hb, rowTotalR, order, out);
    tile_kernel<<<NTILES, 256, 0, stream>>>(hb, labels, order, rowTotalR, rowPosR);
    reduce_loss_kernel<<<64, 256, 0, stream>>>(labels, rowTotalR, rowPosR, out);
}

// Round 8
// 152.665 us; speedup vs baseline: 1.0478x; 1.0478x over previous
//
#include <hip/hip_runtime.h>
#include <hip/hip_bf16.h>

typedef unsigned short u16;
typedef unsigned int u32;
typedef __bf16 bf16x8 __attribute__((ext_vector_type(8)));
typedef float f32x4 __attribute__((ext_vector_type(4)));

#define N_ROWS 8192
#define DIM 512
#define BM 128
#define BN 128
#define BK 64
#define NREP 8             // accumulator replicas
#define TEMP_INV (1.0f / 0.07f)

// round-to-nearest-even float -> bf16 bit pattern
__device__ __forceinline__ u16 f2bf(float f) {
    union { float f; u32 u; } a;
    a.f = f;
    u32 r = a.u + 0x7FFFu + ((a.u >> 16) & 1u);
    return (u16)(r >> 16);
}

// ------- kernel 1: L2-normalize rows -> bf16; zero accs --------------------
__global__ __launch_bounds__(256) void norm_cast_kernel(
        const float* __restrict__ x, u16* __restrict__ hb,
        float* __restrict__ accR /* 2*NREP*N_ROWS floats */,
        float* __restrict__ out) {
    int gid = blockIdx.x * 256 + threadIdx.x;
    if (gid < 2 * NREP * N_ROWS) accR[gid] = 0.f;
    if (gid == 0) out[0] = 0.f;
    int row  = blockIdx.x * 4 + (threadIdx.x >> 6);
    int lane = threadIdx.x & 63;
    const float4* xr = (const float4*)(x + (size_t)row * DIM);
    float4 v0 = xr[lane * 2 + 0];
    float4 v1 = xr[lane * 2 + 1];
    float ss = v0.x * v0.x + v0.y * v0.y + v0.z * v0.z + v0.w * v0.w
             + v1.x * v1.x + v1.y * v1.y + v1.z * v1.z + v1.w * v1.w;
#pragma unroll
    for (int off = 32; off; off >>= 1) ss += __shfl_xor(ss, off);
    float s = 1.0f / fmaxf(sqrtf(ss), 1e-12f);
    uint4 o;
    o.x = (u32)f2bf(v0.x * s) | ((u32)f2bf(v0.y * s) << 16);
    o.y = (u32)f2bf(v0.z * s) | ((u32)f2bf(v0.w * s) << 16);
    o.z = (u32)f2bf(v1.x * s) | ((u32)f2bf(v1.y * s) << 16);
    o.w = (u32)f2bf(v1.z * s) | ((u32)f2bf(v1.w * s) << 16);
    ((uint4*)(hb + (size_t)row * DIM))[lane] = o;
}

// ------- kernel 2: triangular fused tile GEMM + exp + sums -----------------
// Pair schedule (R8): grid 2304 = 9 steps x 256 CUs. Under round-robin
// dispatch block b lands on CU c=b&255, step m=b>>8. Pair p = 4*(c&7)+(c>>3&3)
// owns columns {p, 63-p} (65 tiles — identical for every pair) and lives on
// XCD c&7 only -> per-XCD B set = 1 MB (L2-resident, R4-proven) while every
// CU gets 8-9 tiles (perfect balance, R4's 0..16 fixed). The pair's 8 CUs
// (j=c>>5) walk ti in an 8-wide lockstep window -> A-tiles L2-shared.
// Kernel body identical to R7.
__global__ __launch_bounds__(256) void tile_kernel(
        const u16* __restrict__ hb, const int* __restrict__ labels,
        float* __restrict__ rowTotalR, float* __restrict__ rowPosR) {
    __shared__ __align__(16) u16 ldsA[BM * BK];
    __shared__ __align__(16) u16 ldsB[BN * BK];
    __shared__ int labR[BM];
    __shared__ int labC[BN];
    __shared__ float cT[2][BN], cP[2][BN];   // per wave-row column sums
    __shared__ float rT[2][BM], rP[2][BM];   // per wave-col row sums

    const int b = blockIdx.x;
    const int c = b & 255;          // CU slot (round-robin assumption)
    const int m = b >> 8;           // step 0..8
    const int y = c >> 3;
    const int p = 4 * (c & 7) + (y & 3);    // pair id [0,32)
    const int j = y >> 2;                   // CU within pair [0,8)
    const int t = j + 8 * m;                // tile index within pair
    if (t >= 65) return;                    // tail dead slots only
    int ti, tj;
    if (t <= p) { tj = p; ti = t; }
    else        { tj = 63 - p; ti = t - p - 1; }

    const int rowBase = ti * BM;
    const int colBase = tj * BN;
    const bool isDiag = (ti == tj);
    const int dd = colBase - rowBase;        // diag element iff rloc - cloc == dd
    const int rep = (ti + tj) & (NREP - 1);
    const int tid = threadIdx.x;

    if (tid < 128) labR[tid] = labels[rowBase + tid];
    else           labC[tid - 128] = labels[colBase + tid - 128];

    const int w = tid >> 6;
    const int lane = tid & 63;
    const int wm = (w >> 1) * 64;   // wave row offset in tile
    const int wn = (w & 1) * 64;    // wave col offset in tile
    const int wr = w >> 1;
    const int wc = w & 1;
    const int quad = lane >> 4;
    const int l16 = lane & 15;
    const int sw = l16 & 7;         // xor-swizzle key

    f32x4 acc[4][4];
#pragma unroll
    for (int i = 0; i < 4; ++i)
#pragma unroll
        for (int jj = 0; jj < 4; ++jj)
            acc[i][jj] = (f32x4){0.f, 0.f, 0.f, 0.f};

    for (int k0 = 0; k0 < DIM; k0 += BK) {
        // stage tiles; 16 B chunks xor-swizzled within each 128 B row
#pragma unroll
        for (int s = 0; s < 4; ++s) {
            int seg = tid + s * 256;          // 0..1023
            int r = seg >> 3;                 // 0..127
            int c8 = seg & 7;                 // chunk slot in LDS
            int gc = (k0 >> 3) + (c8 ^ (r & 7));
            const u16* ga = hb + (size_t)(rowBase + r) * DIM + gc * 8;
            const u16* gb = hb + (size_t)(colBase + r) * DIM + gc * 8;
            __builtin_amdgcn_global_load_lds(
                (const __attribute__((address_space(1))) void*)ga,
                (__attribute__((address_space(3))) void*)&ldsA[seg * 8], 16, 0, 0);
            __builtin_amdgcn_global_load_lds(
                (const __attribute__((address_space(1))) void*)gb,
                (__attribute__((address_space(3))) void*)&ldsB[seg * 8], 16, 0, 0);
        }
        __syncthreads();
#pragma unroll
        for (int kk8 = 0; kk8 < 8; kk8 += 4) {   // two K=32 steps
            bf16x8 af[4], bfr[4];
#pragma unroll
            for (int im = 0; im < 4; ++im)
                af[im] = *(const bf16x8*)
                    &ldsA[(wm + im * 16 + l16) * BK + (((kk8 + quad) ^ sw) * 8)];
#pragma unroll
            for (int in = 0; in < 4; ++in)
                bfr[in] = *(const bf16x8*)
                    &ldsB[(wn + in * 16 + l16) * BK + (((kk8 + quad) ^ sw) * 8)];
#pragma unroll
            for (int im = 0; im < 4; ++im)
#pragma unroll
                for (int in = 0; in < 4; ++in)
                    acc[im][in] = __builtin_amdgcn_mfma_f32_16x16x32_bf16(
                        af[im], bfr[in], acc[im][in], 0, 0, 0);
        }
        __syncthreads();
    }

    // ---------------- epilogue ----------------
    // C/D layout: col = l16, row = quad*4 + reg (within each 16x16 frag)
    int lc[4];
#pragma unroll
    for (int in = 0; in < 4; ++in) lc[in] = labC[wn + in * 16 + l16];

    float colT[4] = {0.f, 0.f, 0.f, 0.f}, colP[4] = {0.f, 0.f, 0.f, 0.f};
#pragma unroll
    for (int im = 0; im < 4; ++im) {
        float rowT[4] = {0.f, 0.f, 0.f, 0.f}, rowP[4] = {0.f, 0.f, 0.f, 0.f};
#pragma unroll
        for (int reg = 0; reg < 4; ++reg) {
            int rloc = wm + im * 16 + quad * 4 + reg;
            int li = labR[rloc];
#pragma unroll
            for (int in = 0; in < 4; ++in) {
                int cloc = wn + in * 16 + l16;
                float e = __expf(acc[im][in][reg] * TEMP_INV);
                bool pos = (lc[in] == li) && (rloc - cloc != dd);
                colT[in] += e; rowT[reg] += e;
                if (pos) { colP[in] += e; rowP[reg] += e; }
            }
        }
        if (!isDiag) {
#pragma unroll
            for (int reg = 0; reg < 4; ++reg) {
                float tt = rowT[reg], pp = rowP[reg];
                tt += __shfl_xor(tt, 1); tt += __shfl_xor(tt, 2);
                tt += __shfl_xor(tt, 4); tt += __shfl_xor(tt, 8);
                pp += __shfl_xor(pp, 1); pp += __shfl_xor(pp, 2);
                pp += __shfl_xor(pp, 4); pp += __shfl_xor(pp, 8);
                if (l16 == 0) {
                    int rloc = wm + im * 16 + quad * 4 + reg;
                    rT[wc][rloc] = tt;   // distinct rloc per (im,quad,reg)
                    rP[wc][rloc] = pp;
                }
            }
        }
    }
#pragma unroll
    for (int in = 0; in < 4; ++in) {
        float tt = colT[in], pp = colP[in];
        tt += __shfl_xor(tt, 16); tt += __shfl_xor(tt, 32);
        pp += __shfl_xor(pp, 16); pp += __shfl_xor(pp, 32);
        if (quad == 0) {
            int cloc = wn + in * 16 + l16;
            cT[wr][cloc] = tt;
            cP[wr][cloc] = pp;
        }
    }
    __syncthreads();
    float* rowTotal = rowTotalR + rep * N_ROWS;
    float* rowPos   = rowPosR   + rep * N_ROWS;
    if (tid < 128) {
        atomicAdd(&rowTotal[colBase + tid], cT[0][tid] + cT[1][tid]);
        if (!isDiag) atomicAdd(&rowTotal[rowBase + tid], rT[0][tid] + rT[1][tid]);
    } else {
        int t2 = tid - 128;
        atomicAdd(&rowPos[colBase + t2], cP[0][t2] + cP[1][t2]);
        if (!isDiag) atomicAdd(&rowPos[rowBase + t2], rP[0][t2] + rP[1][t2]);
    }
}

// ------- kernel 3: fold replicas + histogram + loss (64 blocks) ------------
__global__ __launch_bounds__(256) void reduce_loss_kernel(
        const int* __restrict__ labels, const float* __restrict__ rowTotalR,
        const float* __restrict__ rowPosR, float* __restrict__ out) {
    __shared__ int hist[128];
    __shared__ float red[256];
    int tid = threadIdx.x;
    if (tid < 128) hist[tid] = 0;
    __syncthreads();
    for (int i = tid; i < N_ROWS; i += 256)
        atomicAdd(&hist[labels[i] & 127], 1);
    __syncthreads();
    float sacc = 0.f;
    if (tid < 128) {
        int row = blockIdx.x * 128 + tid;
        float T = 0.f, P = 0.f;
#pragma unroll
        for (int r = 0; r < NREP; ++r) {
            T += rowTotalR[r * N_ROWS + row];
            P += rowPosR[r * N_ROWS + row];
        }
        float c = (float)(hist[labels[row] & 127] - 1);
        sacc = logf((P / (c + 1e-9f)) / T);
    }
    red[tid] = sacc;
    __syncthreads();
    for (int st = 128; st; st >>= 1) {
        if (tid < st) red[tid] += red[tid + st];
        __syncthreads();
    }
    if (tid == 0) atomicAdd(out, -red[0] / (float)N_ROWS);
}

extern "C" void kernel_launch(void* const* d_in, const int* in_sizes, int n_in,
                              void* d_out, int out_size, void* d_ws, size_t ws_size,
                              hipStream_t stream) {
    const float* hidden = (const float*)d_in[0];
    const int* labels   = (const int*)d_in[1];
    float* out = (float*)d_out;

    char* ws = (char*)d_ws;
    u16* hb = (u16*)ws;                                          // 8 MB
    float* rowTotalR = (float*)(ws + (size_t)N_ROWS * DIM * 2);  // NREP*8192 f
    float* rowPosR   = rowTotalR + NREP * N_ROWS;                // NREP*8192 f

    norm_cast_kernel<<<N_ROWS / 4, 256, 0, stream>>>(hidden, hb, rowTotalR, out);
    tile_kernel<<<9 * 256, 256, 0, stream>>>(hb, labels, rowTotalR, rowPosR);
    reduce_loss_kernel<<<64, 256, 0, stream>>>(labels, rowTotalR, rowPosR, out);
}

// Round 10
// 119.492 us; speedup vs baseline: 1.3387x; 1.2776x over previous
//
#include <hip/hip_runtime.h>
#include <hip/hip_bf16.h>

typedef unsigned short u16;
typedef unsigned int u32;
typedef float f32x4 __attribute__((ext_vector_type(4)));

#define N_ROWS 8192
#define DIM 512
#define BM 128
#define BN 128
#define NREP 8             // accumulator replicas
// sqrt(1/0.07): folded into stored fp8 so MFMA emits sim/T directly
#define SCALE 3.77964473f

// ------- kernel 1: L2-normalize rows -> fp8 e4m3 (pre-scaled); zero accs ---
__global__ __launch_bounds__(256) void norm_cast_kernel(
        const float* __restrict__ x, u32* __restrict__ hb8,
        float* __restrict__ accR /* 2*NREP*N_ROWS floats */,
        float* __restrict__ out) {
    int gid = blockIdx.x * 256 + threadIdx.x;
    if (gid < 2 * NREP * N_ROWS) accR[gid] = 0.f;
    if (gid == 0) out[0] = 0.f;
    int row  = blockIdx.x * 4 + (threadIdx.x >> 6);
    int lane = threadIdx.x & 63;
    const float4* xr = (const float4*)(x + (size_t)row * DIM);
    float4 v0 = xr[lane * 2 + 0];
    float4 v1 = xr[lane * 2 + 1];
    float ss = v0.x * v0.x + v0.y * v0.y + v0.z * v0.z + v0.w * v0.w
             + v1.x * v1.x + v1.y * v1.y + v1.z * v1.z + v1.w * v1.w;
#pragma unroll
    for (int off = 32; off; off >>= 1) ss += __shfl_xor(ss, off);
    float s = SCALE / fmaxf(sqrtf(ss), 1e-12f);
    // pack 8 fp8 (OCP e4m3 on gfx950, RNE+sat in HW)
    int w0 = __builtin_amdgcn_cvt_pk_fp8_f32(v0.x * s, v0.y * s, 0, false);
    w0     = __builtin_amdgcn_cvt_pk_fp8_f32(v0.z * s, v0.w * s, w0, true);
    int w1 = __builtin_amdgcn_cvt_pk_fp8_f32(v1.x * s, v1.y * s, 0, false);
    w1     = __builtin_amdgcn_cvt_pk_fp8_f32(v1.z * s, v1.w * s, w1, true);
    uint2 o; o.x = (u32)w0; o.y = (u32)w1;
    ((uint2*)((char*)hb8 + (size_t)row * DIM + lane * 8))[0] = o;
}

// stage helper: immediate offset must be a constant-expression for
// __builtin_amdgcn_global_load_lds -> template parameter (R9 compile fix).
template <int K0OFF>
__device__ __forceinline__ void stage_tiles(
        const char* const* gA, const char* const* gB,
        char* ldsA, char* ldsB, int tid) {
#pragma unroll
    for (int s2 = 0; s2 < 4; ++s2) {
        int seg = tid + s2 * 256;
        __builtin_amdgcn_global_load_lds(
            (const __attribute__((address_space(1))) void*)gA[s2],
            (__attribute__((address_space(3))) void*)&ldsA[seg * 16],
            16, K0OFF, 0);
        __builtin_amdgcn_global_load_lds(
            (const __attribute__((address_space(1))) void*)gB[s2],
            (__attribute__((address_space(3))) void*)&ldsB[seg * 16],
            16, K0OFF, 0);
    }
}

// ------- kernel 2: triangular fused tile GEMM (fp8) + exp + sums -----------
// R8 pair schedule unchanged (FETCH 27.6 MB, balance 8-9 tiles/CU — proven).
// Body: fp8 e4m3 operands (half bytes), BK=128 (8 barriers/tile vs 16),
// full k0 unroll with immediate global offsets (no per-iter staging VALU).
// LDS row stride 128 B; 16-B slot s holds global chunk s^(r&7) -> ds_read_b64
// frag reads are <=2-way bank-aliased (free, m136).
__global__ __launch_bounds__(256) void tile_kernel(
        const char* __restrict__ hb8, const int* __restrict__ labels,
        float* __restrict__ rowTotalR, float* __restrict__ rowPosR) {
    __shared__ __align__(16) char ldsA[BM * 128];   // 16 KB
    __shared__ __align__(16) char ldsB[BN * 128];   // 16 KB
    __shared__ int labR[BM];
    __shared__ int labC[BN];
    __shared__ float cT[2][BN], cP[2][BN];
    __shared__ float rT[2][BM], rP[2][BM];

    const int b = blockIdx.x;
    const int c = b & 255;          // CU slot (round-robin)
    const int m = b >> 8;           // step 0..8
    const int y = c >> 3;
    const int p = 4 * (c & 7) + (y & 3);    // pair id [0,32)
    const int j = y >> 2;                   // CU within pair [0,8)
    const int t = j + 8 * m;                // tile index within pair
    if (t >= 65) return;
    int ti, tj;
    if (t <= p) { tj = p; ti = t; }
    else        { tj = 63 - p; ti = t - p - 1; }

    const int rowBase = ti * BM;
    const int colBase = tj * BN;
    const bool isDiag = (ti == tj);
    const int dd = colBase - rowBase;
    const int rep = (ti + tj) & (NREP - 1);
    const int tid = threadIdx.x;

    if (tid < 128) labR[tid] = labels[rowBase + tid];
    else           labC[tid - 128] = labels[colBase + tid - 128];

    const int w = tid >> 6;
    const int lane = tid & 63;
    const int wm = (w >> 1) * 64;
    const int wn = (w & 1) * 64;
    const int wr = w >> 1;
    const int wc = w & 1;
    const int quad = lane >> 4;
    const int l16 = lane & 15;

    // staging bases (computed once; k0 advances via immediate offset)
    const char* gA[4]; const char* gB[4];
#pragma unroll
    for (int s2 = 0; s2 < 4; ++s2) {
        int seg = tid + s2 * 256;         // 0..1023
        int r = seg >> 3;                 // 0..127
        int sl = seg & 7;                 // LDS 16-B slot
        int g = sl ^ (r & 7);             // global 16-B chunk within 128-B row-slice
        gA[s2] = hb8 + (size_t)(rowBase + r) * DIM + g * 16;
        gB[s2] = hb8 + (size_t)(colBase + r) * DIM + g * 16;
    }

    f32x4 acc[4][4];
#pragma unroll
    for (int i = 0; i < 4; ++i)
#pragma unroll
        for (int jj = 0; jj < 4; ++jj)
            acc[i][jj] = (f32x4){0.f, 0.f, 0.f, 0.f};

#pragma unroll
    for (int k0 = 0; k0 < 4; ++k0) {      // BK=128 bytes, imm offset k0*128
        switch (k0) {
            case 0: stage_tiles<0>(gA, gB, ldsA, ldsB, tid); break;
            case 1: stage_tiles<128>(gA, gB, ldsA, ldsB, tid); break;
            case 2: stage_tiles<256>(gA, gB, ldsA, ldsB, tid); break;
            default: stage_tiles<384>(gA, gB, ldsA, ldsB, tid); break;
        }
        __syncthreads();                  // drain + barrier
#pragma unroll
        for (int kk = 0; kk < 4; ++kk) {  // four K=32 MFMA steps per BK=128
            long af[4], bfr[4];
#pragma unroll
            for (int im = 0; im < 4; ++im) {
                int row = wm + im * 16 + l16;
                int c4 = kk * 2 + (quad >> 1);
                int sl = c4 ^ (row & 7);
                af[im] = *(const long*)&ldsA[row * 128 + sl * 16 + (quad & 1) * 8];
            }
#pragma unroll
            for (int in = 0; in < 4; ++in) {
                int col = wn + in * 16 + l16;
                int c4 = kk * 2 + (quad >> 1);
                int sl = c4 ^ (col & 7);
                bfr[in] = *(const long*)&ldsB[col * 128 + sl * 16 + (quad & 1) * 8];
            }
#pragma unroll
            for (int im = 0; im < 4; ++im)
#pragma unroll
                for (int in = 0; in < 4; ++in)
                    acc[im][in] = __builtin_amdgcn_mfma_f32_16x16x32_fp8_fp8(
                        af[im], bfr[in], acc[im][in], 0, 0, 0);
        }
        __syncthreads();                  // protect buffers before next stage
    }

    // ---------------- epilogue (acc already = sim/T) ----------------
    int lc[4];
#pragma unroll
    for (int in = 0; in < 4; ++in) lc[in] = labC[wn + in * 16 + l16];

    float colT[4] = {0.f, 0.f, 0.f, 0.f}, colP[4] = {0.f, 0.f, 0.f, 0.f};
#pragma unroll
    for (int im = 0; im < 4; ++im) {
        float rowT[4] = {0.f, 0.f, 0.f, 0.f}, rowP[4] = {0.f, 0.f, 0.f, 0.f};
#pragma unroll
        for (int reg = 0; reg < 4; ++reg) {
            int rloc = wm + im * 16 + quad * 4 + reg;
            int li = labR[rloc];
#pragma unroll
            for (int in = 0; in < 4; ++in) {
                int cloc = wn + in * 16 + l16;
                float e = __expf(acc[im][in][reg]);
                bool pos = (lc[in] == li) && (rloc - cloc != dd);
                colT[in] += e; rowT[reg] += e;
                if (pos) { colP[in] += e; rowP[reg] += e; }
            }
        }
        if (!isDiag) {
#pragma unroll
            for (int reg = 0; reg < 4; ++reg) {
                float tt = rowT[reg], pp = rowP[reg];
                tt += __shfl_xor(tt, 1); tt += __shfl_xor(tt, 2);
                tt += __shfl_xor(tt, 4); tt += __shfl_xor(tt, 8);
                pp += __shfl_xor(pp, 1); pp += __shfl_xor(pp, 2);
                pp += __shfl_xor(pp, 4); pp += __shfl_xor(pp, 8);
                if (l16 == 0) {
                    int rloc = wm + im * 16 + quad * 4 + reg;
                    rT[wc][rloc] = tt;
                    rP[wc][rloc] = pp;
                }
            }
        }
    }
#pragma unroll
    for (int in = 0; in < 4; ++in) {
        float tt = colT[in], pp = colP[in];
        tt += __shfl_xor(tt, 16); tt += __shfl_xor(tt, 32);
        pp += __shfl_xor(pp, 16); pp += __shfl_xor(pp, 32);
        if (quad == 0) {
            int cloc = wn + in * 16 + l16;
            cT[wr][cloc] = tt;
            cP[wr][cloc] = pp;
        }
    }
    __syncthreads();
    float* rowTotal = rowTotalR + rep * N_ROWS;
    float* rowPos   = rowPosR   + rep * N_ROWS;
    if (tid < 128) {
        atomicAdd(&rowTotal[colBase + tid], cT[0][tid] + cT[1][tid]);
        if (!isDiag) atomicAdd(&rowTotal[rowBase + tid], rT[0][tid] + rT[1][tid]);
    } else {
        int t2 = tid - 128;
        atomicAdd(&rowPos[colBase + t2], cP[0][t2] + cP[1][t2]);
        if (!isDiag) atomicAdd(&rowPos[rowBase + t2], rP[0][t2] + rP[1][t2]);
    }
}

// ------- kernel 3: fold replicas + histogram + loss (64 blocks) ------------
__global__ __launch_bounds__(256) void reduce_loss_kernel(
        const int* __restrict__ labels, const float* __restrict__ rowTotalR,
        const float* __restrict__ rowPosR, float* __restrict__ out) {
    __shared__ int hist[128];
    __shared__ float red[256];
    int tid = threadIdx.x;
    if (tid < 128) hist[tid] = 0;
    __syncthreads();
    for (int i = tid; i < N_ROWS; i += 256)
        atomicAdd(&hist[labels[i] & 127], 1);
    __syncthreads();
    float sacc = 0.f;
    if (tid < 128) {
        int row = blockIdx.x * 128 + tid;
        float T = 0.f, P = 0.f;
#pragma unroll
        for (int r = 0; r < NREP; ++r) {
            T += rowTotalR[r * N_ROWS + row];
            P += rowPosR[r * N_ROWS + row];
        }
        float cc = (float)(hist[labels[row] & 127] - 1);
        sacc = logf((P / (cc + 1e-9f)) / T);
    }
    red[tid] = sacc;
    __syncthreads();
    for (int st = 128; st; st >>= 1) {
        if (tid < st) red[tid] += red[tid + st];
        __syncthreads();
    }
    if (tid == 0) atomicAdd(out, -red[0] / (float)N_ROWS);
}

extern "C" void kernel_launch(void* const* d_in, const int* in_sizes, int n_in,
                              void* d_out, int out_size, void* d_ws, size_t ws_size,
                              hipStream_t stream) {
    const float* hidden = (const float*)d_in[0];
    const int* labels   = (const int*)d_in[1];
    float* out = (float*)d_out;

    char* ws = (char*)d_ws;
    char* hb8 = ws;                                          // 8192*512 = 4 MB
    float* rowTotalR = (float*)(ws + (size_t)N_ROWS * DIM);  // NREP*8192 f
    float* rowPosR   = rowTotalR + NREP * N_ROWS;            // NREP*8192 f

    norm_cast_kernel<<<N_ROWS / 4, 256, 0, stream>>>(hidden, (u32*)hb8, rowTotalR, out);
    tile_kernel<<<9 * 256, 256, 0, stream>>>(hb8, labels, rowTotalR, rowPosR);
    reduce_loss_kernel<<<64, 256, 0, stream>>>(labels, rowTotalR, rowPosR, out);
}